// Round 1
// baseline (421.586 us; speedup 1.0000x reference)
//
#include <hip/hip_runtime.h>
#include <math.h>

#define NN 20000
#define NE 640000
#define HD 128
#define NLAYERS 3

// ---------------- encoder: h[n][k] = x[n]*enc_w[k] + enc_b[k] ----------------
__global__ __launch_bounds__(256) void k_encoder(const float* __restrict__ x,
                                                 const float* __restrict__ enc_w,
                                                 const float* __restrict__ enc_b,
                                                 float* __restrict__ h) {
    int t = blockIdx.x * 256 + threadIdx.x;
    if (t >= NN * HD) return;
    int n = t >> 7, k = t & 127;
    h[t] = fmaf(x[n], enc_w[k], enc_b[k]);
}

// ---------------- CSR build ----------------
__global__ __launch_bounds__(256) void k_fill_zero(int* __restrict__ p, int n) {
    int t = blockIdx.x * 256 + threadIdx.x;
    if (t < n) p[t] = 0;
}

__global__ __launch_bounds__(256) void k_hist(const int* __restrict__ dst, int* __restrict__ cnt) {
    int e = blockIdx.x * 256 + threadIdx.x;
    if (e >= NE) return;
    atomicAdd(&cnt[dst[e]], 1);
}

// single block, 1024 threads, 20 items each -> exclusive scan of cnt[0..NN)
__global__ __launch_bounds__(1024) void k_scan(const int* __restrict__ cnt,
                                               int* __restrict__ row_ptr,
                                               int* __restrict__ cursor) {
    __shared__ int sums[1024];
    int t = threadIdx.x;
    int base = t * 20;
    int local[20];
    int s = 0;
#pragma unroll
    for (int i = 0; i < 20; i++) {
        int idx = base + i;
        int v = (idx < NN) ? cnt[idx] : 0;
        local[i] = s;
        s += v;
    }
    sums[t] = s;
    __syncthreads();
    for (int off = 1; off < 1024; off <<= 1) {
        int v = (t >= off) ? sums[t - off] : 0;
        __syncthreads();
        sums[t] += v;
        __syncthreads();
    }
    int offset = (t == 0) ? 0 : sums[t - 1];
#pragma unroll
    for (int i = 0; i < 20; i++) {
        int idx = base + i;
        if (idx < NN) {
            int p = offset + local[i];
            row_ptr[idx] = p;
            cursor[idx] = p;
        }
    }
    if (t == 1023) row_ptr[NN] = sums[1023];
}

__global__ __launch_bounds__(256) void k_scatter(const int* __restrict__ src,
                                                 const int* __restrict__ dst,
                                                 const float* __restrict__ ea,
                                                 int* __restrict__ cursor,
                                                 int* __restrict__ src_sorted,
                                                 float* __restrict__ ea_sorted) {
    int e = blockIdx.x * 256 + threadIdx.x;
    if (e >= NE) return;
    int d = dst[e];
    int pos = atomicAdd(&cursor[d], 1);
    src_sorted[pos] = src[e];
    ea_sorted[pos] = ea[e];
}

// ---------------- node GEMM 1: A = h@Wd + msg_b ; B = h@Ws ----------------
// 128 threads, 8 nodes per block
__global__ __launch_bounds__(128) void k_mm1(const float* __restrict__ h,
                                             const float* __restrict__ msg_w,
                                             const float* __restrict__ msg_b,
                                             float* __restrict__ A,
                                             float* __restrict__ B) {
    __shared__ float hs[8][HD];
    int t = threadIdx.x;
    int n0 = blockIdx.x * 8;
#pragma unroll
    for (int r = 0; r < 8; r++) hs[r][t] = h[(n0 + r) * HD + t];
    __syncthreads();
    float a[8], b[8];
    float mb = msg_b[t];
#pragma unroll
    for (int r = 0; r < 8; r++) { a[r] = mb; b[r] = 0.f; }
#pragma unroll 4
    for (int c = 0; c < HD; c++) {
        float wA = msg_w[c * HD + t];
        float wB = msg_w[(HD + c) * HD + t];
#pragma unroll
        for (int r = 0; r < 8; r++) {
            a[r] = fmaf(hs[r][c], wA, a[r]);
            b[r] = fmaf(hs[r][c], wB, b[r]);
        }
    }
#pragma unroll
    for (int r = 0; r < 8; r++) {
        A[(n0 + r) * HD + t] = a[r];
        B[(n0 + r) * HD + t] = b[r];
    }
}

// ---------------- aggregation: aggr[i] = relu(A[i] + max_e(B[src]+ea*w256)) ----------------
// one block (128 threads) per node; writes aggr in-place into A
__global__ __launch_bounds__(128) void k_aggr(const float* __restrict__ B,
                                              float* __restrict__ A,
                                              const int* __restrict__ row_ptr,
                                              const int* __restrict__ src_sorted,
                                              const float* __restrict__ ea_sorted,
                                              const float* __restrict__ msg_w) {
    int i = blockIdx.x;
    int t = threadIdx.x;
    int e0 = row_ptr[i], e1 = row_ptr[i + 1];
    float w256 = msg_w[256 * HD + t];
    float m = -INFINITY;
    int e = e0;
    // unroll-by-2 for two loads in flight
    for (; e + 1 < e1; e += 2) {
        int s0 = src_sorted[e], s1 = src_sorted[e + 1];
        float ea0 = ea_sorted[e], ea1 = ea_sorted[e + 1];
        float v0 = fmaf(ea0, w256, B[s0 * HD + t]);
        float v1 = fmaf(ea1, w256, B[s1 * HD + t]);
        m = fmaxf(m, fmaxf(v0, v1));
    }
    if (e < e1) {
        int s0 = src_sorted[e];
        float ea0 = ea_sorted[e];
        m = fmaxf(m, fmaf(ea0, w256, B[s0 * HD + t]));
    }
    float aggr = fmaxf(A[i * HD + t] + m, 0.f);
    A[i * HD + t] = aggr;
}

// ---------------- node GEMM 2: h_out = relu(h@Wu_top + aggr@Wu_bot + upd_b) ----------------
__global__ __launch_bounds__(128) void k_mm2(const float* __restrict__ h,
                                             const float* __restrict__ aggr,
                                             const float* __restrict__ upd_w,
                                             const float* __restrict__ upd_b,
                                             float* __restrict__ hout) {
    __shared__ float hs[8][HD];
    __shared__ float as[8][HD];
    int t = threadIdx.x;
    int n0 = blockIdx.x * 8;
#pragma unroll
    for (int r = 0; r < 8; r++) {
        hs[r][t] = h[(n0 + r) * HD + t];
        as[r][t] = aggr[(n0 + r) * HD + t];
    }
    __syncthreads();
    float acc[8];
    float ub = upd_b[t];
#pragma unroll
    for (int r = 0; r < 8; r++) acc[r] = ub;
#pragma unroll 4
    for (int c = 0; c < HD; c++) {
        float w1 = upd_w[c * HD + t];
        float w2 = upd_w[(HD + c) * HD + t];
#pragma unroll
        for (int r = 0; r < 8; r++) {
            acc[r] = fmaf(hs[r][c], w1, acc[r]);
            acc[r] = fmaf(as[r][c], w2, acc[r]);
        }
    }
#pragma unroll
    for (int r = 0; r < 8; r++) hout[(n0 + r) * HD + t] = fmaxf(acc[r], 0.f);
}

// ---------------- decoder + per-block term partial ----------------
// 256 threads = 4 waves, one node per wave
__global__ __launch_bounds__(256) void k_dec(const float* __restrict__ h,
                                             const float* __restrict__ dec_w,
                                             const float* __restrict__ dec_b,
                                             const float* __restrict__ term_w,
                                             float* __restrict__ out,
                                             float* __restrict__ partials) {
    __shared__ float red[4];
    int t = threadIdx.x;
    int wave = t >> 6, lane = t & 63;
    int n = blockIdx.x * 4 + wave;
    float h0 = h[n * HD + lane], h1 = h[n * HD + 64 + lane];
    float s1 = fmaf(h0, dec_w[lane], h1 * dec_w[64 + lane]);
    float s2 = fmaf(h0, term_w[lane], h1 * term_w[64 + lane]);
#pragma unroll
    for (int off = 32; off; off >>= 1) {
        s1 += __shfl_xor(s1, off);
        s2 += __shfl_xor(s2, off);
    }
    if (lane == 0) {
        out[n] = 1.f / (1.f + expf(-(s1 + dec_b[0])));
        red[wave] = s2;
    }
    __syncthreads();
    if (t == 0) partials[blockIdx.x] = red[0] + red[1] + red[2] + red[3];
}

__global__ __launch_bounds__(256) void k_term(const float* __restrict__ partials,
                                              const float* __restrict__ term_b,
                                              float* __restrict__ out) {
    __shared__ float red[256];
    int t = threadIdx.x;
    float s = 0.f;
    for (int i = t; i < 5000; i += 256) s += partials[i];
    red[t] = s;
    __syncthreads();
    for (int off = 128; off; off >>= 1) {
        if (t < off) red[t] += red[t + off];
        __syncthreads();
    }
    if (t == 0) {
        float m = red[0] / (float)NN;
        out[NN] = 1.f / (1.f + expf(-(m + term_b[0])));
    }
}

extern "C" void kernel_launch(void* const* d_in, const int* in_sizes, int n_in,
                              void* d_out, int out_size, void* d_ws, size_t ws_size,
                              hipStream_t stream) {
    const float* x        = (const float*)d_in[0];
    const int*   eidx     = (const int*)d_in[1];
    const float* eattr    = (const float*)d_in[2];
    const float* enc_w    = (const float*)d_in[3];
    const float* enc_b    = (const float*)d_in[4];
    const float* msg_w    = (const float*)d_in[5];
    const float* msg_b    = (const float*)d_in[6];
    const float* upd_w    = (const float*)d_in[7];
    const float* upd_b    = (const float*)d_in[8];
    const float* dec_w    = (const float*)d_in[9];
    const float* dec_b    = (const float*)d_in[10];
    const float* term_w   = (const float*)d_in[11];
    const float* term_b   = (const float*)d_in[12];
    float* out = (float*)d_out;

    const int* src = eidx;          // edge_index[0] = source j
    const int* dst = eidx + NE;     // edge_index[1] = target i

    char* ws = (char*)d_ws;
    size_t off = 0;
    auto alloc = [&](size_t bytes) -> void* {
        void* p = ws + off;
        off += (bytes + 255) & ~size_t(255);
        return p;
    };
    float* hA        = (float*)alloc((size_t)NN * HD * 4);
    float* hB        = (float*)alloc((size_t)NN * HD * 4);
    float* Abuf      = (float*)alloc((size_t)NN * HD * 4);
    float* Bbuf      = (float*)alloc((size_t)NN * HD * 4);
    int*   src_sorted= (int*)  alloc((size_t)NE * 4);
    float* ea_sorted = (float*)alloc((size_t)NE * 4);
    int*   row_ptr   = (int*)  alloc((size_t)(NN + 1) * 4);
    int*   cnt       = (int*)  alloc((size_t)NN * 4);
    int*   cursor    = (int*)  alloc((size_t)NN * 4);
    float* partials  = (float*)alloc((size_t)5000 * 4);

    // encoder
    k_encoder<<<(NN * HD + 255) / 256, 256, 0, stream>>>(x, enc_w, enc_b, hA);

    // CSR build (by dst)
    k_fill_zero<<<(NN + 255) / 256, 256, 0, stream>>>(cnt, NN);
    k_hist<<<(NE + 255) / 256, 256, 0, stream>>>(dst, cnt);
    k_scan<<<1, 1024, 0, stream>>>(cnt, row_ptr, cursor);
    k_scatter<<<(NE + 255) / 256, 256, 0, stream>>>(src, dst, eattr, cursor, src_sorted, ea_sorted);

    float* hin = hA;
    float* hout = hB;
    for (int l = 0; l < NLAYERS; l++) {
        k_mm1<<<NN / 8, 128, 0, stream>>>(hin, msg_w, msg_b, Abuf, Bbuf);
        k_aggr<<<NN, 128, 0, stream>>>(Bbuf, Abuf, row_ptr, src_sorted, ea_sorted, msg_w);
        k_mm2<<<NN / 8, 128, 0, stream>>>(hin, Abuf, upd_w, upd_b, hout);
        float* tmp = hin; hin = hout; hout = tmp;
    }

    // decoder + termination
    k_dec<<<NN / 4, 256, 0, stream>>>(hin, dec_w, dec_b, term_w, out, partials);
    k_term<<<1, 256, 0, stream>>>(partials, term_b, out);
}

// Round 2
// 400.441 us; speedup vs baseline: 1.0528x; 1.0528x over previous
//
#include <hip/hip_runtime.h>
#include <math.h>

#define NN 20000
#define NE 640000
#define HD 128
#define NLAYERS 3
#define NPART 8
#define PART_SZ (NN / NPART)   // 2500

// ---------------- CSR build ----------------
__global__ __launch_bounds__(256) void k_fill_zero(int* __restrict__ p, int n) {
    int t = blockIdx.x * 256 + threadIdx.x;
    if (t < n) p[t] = 0;
}

__global__ __launch_bounds__(256) void k_hist(const int* __restrict__ dst, int* __restrict__ cnt) {
    int e = blockIdx.x * 256 + threadIdx.x;
    if (e >= NE) return;
    atomicAdd(&cnt[dst[e]], 1);
}

// single block, 1024 threads, 20 items each -> exclusive scan of cnt[0..NN)
__global__ __launch_bounds__(1024) void k_scan(const int* __restrict__ cnt,
                                               int* __restrict__ row_ptr,
                                               int* __restrict__ cursor) {
    __shared__ int sums[1024];
    int t = threadIdx.x;
    int base = t * 20;
    int local[20];
    int s = 0;
#pragma unroll
    for (int i = 0; i < 20; i++) {
        int idx = base + i;
        int v = (idx < NN) ? cnt[idx] : 0;
        local[i] = s;
        s += v;
    }
    sums[t] = s;
    __syncthreads();
    for (int off = 1; off < 1024; off <<= 1) {
        int v = (t >= off) ? sums[t - off] : 0;
        __syncthreads();
        sums[t] += v;
        __syncthreads();
    }
    int offset = (t == 0) ? 0 : sums[t - 1];
#pragma unroll
    for (int i = 0; i < 20; i++) {
        int idx = base + i;
        if (idx < NN) {
            int p = offset + local[i];
            row_ptr[idx] = p;
            cursor[idx] = p;
        }
    }
    if (t == 1023) row_ptr[NN] = sums[1023];
}

// Partitioned scatter: partition = blockIdx & 7 (= XCD on default round-robin
// dispatch), each partition handles a contiguous dst range so its scattered
// int2 writes land in a ~640 KB region resident in that XCD's L2.
__global__ __launch_bounds__(256) void k_scatter(const int* __restrict__ src,
                                                 const int* __restrict__ dst,
                                                 const float* __restrict__ ea,
                                                 int* __restrict__ cursor,
                                                 int2* __restrict__ edges) {
    int part = blockIdx.x & (NPART - 1);
    int blk = blockIdx.x >> 3;
    int nblk = gridDim.x >> 3;
    int lo = part * PART_SZ;
    for (int e = blk * 256 + threadIdx.x; e < NE; e += nblk * 256) {
        int d = dst[e];
        if ((unsigned)(d - lo) < (unsigned)PART_SZ) {
            int pos = atomicAdd(&cursor[d], 1);
            edges[pos] = make_int2(src[e], __float_as_int(ea[e]));
        }
    }
}

// ---------------- encoder fused with mm1: h = x*enc_w+enc_b; A=h@Wd+mb; B=h@Ws ----------------
__global__ __launch_bounds__(128) void k_enc_mm1(const float* __restrict__ x,
                                                 const float* __restrict__ enc_w,
                                                 const float* __restrict__ enc_b,
                                                 const float* __restrict__ msg_w,
                                                 const float* __restrict__ msg_b,
                                                 float* __restrict__ h,
                                                 float* __restrict__ A,
                                                 float* __restrict__ B) {
    __shared__ float hs[8][HD];
    int t = threadIdx.x;
    int n0 = blockIdx.x * 8;
    float ew = enc_w[t], eb = enc_b[t];
#pragma unroll
    for (int r = 0; r < 8; r++) {
        float v = fmaf(x[n0 + r], ew, eb);
        hs[r][t] = v;
        h[(n0 + r) * HD + t] = v;
    }
    __syncthreads();
    float a[8], b[8];
    float mb = msg_b[t];
#pragma unroll
    for (int r = 0; r < 8; r++) { a[r] = mb; b[r] = 0.f; }
#pragma unroll 4
    for (int c = 0; c < HD; c++) {
        float wA = msg_w[c * HD + t];
        float wB = msg_w[(HD + c) * HD + t];
#pragma unroll
        for (int r = 0; r < 8; r++) {
            a[r] = fmaf(hs[r][c], wA, a[r]);
            b[r] = fmaf(hs[r][c], wB, b[r]);
        }
    }
#pragma unroll
    for (int r = 0; r < 8; r++) {
        A[(n0 + r) * HD + t] = a[r];
        B[(n0 + r) * HD + t] = b[r];
    }
}

// ---------------- aggregation: A[i] = relu(A[i] + max_e(B[src]+ea*w256)) ----------------
__global__ __launch_bounds__(128) void k_aggr(const float* __restrict__ B,
                                              float* __restrict__ A,
                                              const int* __restrict__ row_ptr,
                                              const int2* __restrict__ edges,
                                              const float* __restrict__ msg_w) {
    int i = blockIdx.x;
    int t = threadIdx.x;
    int e0 = row_ptr[i], e1 = row_ptr[i + 1];
    float w256 = msg_w[256 * HD + t];
    float m = -INFINITY;
    int e = e0;
    for (; e + 3 < e1; e += 4) {
        int2 p0 = edges[e], p1 = edges[e + 1], p2 = edges[e + 2], p3 = edges[e + 3];
        float v0 = fmaf(__int_as_float(p0.y), w256, B[(size_t)p0.x * HD + t]);
        float v1 = fmaf(__int_as_float(p1.y), w256, B[(size_t)p1.x * HD + t]);
        float v2 = fmaf(__int_as_float(p2.y), w256, B[(size_t)p2.x * HD + t]);
        float v3 = fmaf(__int_as_float(p3.y), w256, B[(size_t)p3.x * HD + t]);
        m = fmaxf(m, fmaxf(fmaxf(v0, v1), fmaxf(v2, v3)));
    }
    for (; e < e1; e++) {
        int2 p0 = edges[e];
        m = fmaxf(m, fmaf(__int_as_float(p0.y), w256, B[(size_t)p0.x * HD + t]));
    }
    A[i * HD + t] = fmaxf(A[i * HD + t] + m, 0.f);
}

// ---------------- fused update(l) + mm1(l+1) ----------------
// hout = relu(h@Wu1 + aggr@Wu2 + ub); then A=hout@Wd+mb, B=hout@Ws
__global__ __launch_bounds__(128) void k_mm2_mm1(const float* __restrict__ h,
                                                 const float* __restrict__ aggr,
                                                 const float* __restrict__ upd_w,
                                                 const float* __restrict__ upd_b,
                                                 const float* __restrict__ msg_w,
                                                 const float* __restrict__ msg_b,
                                                 float* __restrict__ hout,
                                                 float* __restrict__ A,
                                                 float* __restrict__ B) {
    __shared__ float hs[8][HD];
    __shared__ float as[8][HD];
    int t = threadIdx.x;
    int n0 = blockIdx.x * 8;
#pragma unroll
    for (int r = 0; r < 8; r++) {
        hs[r][t] = h[(n0 + r) * HD + t];
        as[r][t] = aggr[(n0 + r) * HD + t];
    }
    __syncthreads();
    float acc[8];
    float ub = upd_b[t];
#pragma unroll
    for (int r = 0; r < 8; r++) acc[r] = ub;
#pragma unroll 4
    for (int c = 0; c < HD; c++) {
        float w1 = upd_w[c * HD + t];
        float w2 = upd_w[(HD + c) * HD + t];
#pragma unroll
        for (int r = 0; r < 8; r++) {
            acc[r] = fmaf(hs[r][c], w1, acc[r]);
            acc[r] = fmaf(as[r][c], w2, acc[r]);
        }
    }
    __syncthreads();   // everyone done reading hs before overwrite
#pragma unroll
    for (int r = 0; r < 8; r++) {
        float v = fmaxf(acc[r], 0.f);
        hout[(n0 + r) * HD + t] = v;
        hs[r][t] = v;
    }
    __syncthreads();
    // mm1 on the fresh h
    float a[8], b[8];
    float mb = msg_b[t];
#pragma unroll
    for (int r = 0; r < 8; r++) { a[r] = mb; b[r] = 0.f; }
#pragma unroll 4
    for (int c = 0; c < HD; c++) {
        float wA = msg_w[c * HD + t];
        float wB = msg_w[(HD + c) * HD + t];
#pragma unroll
        for (int r = 0; r < 8; r++) {
            a[r] = fmaf(hs[r][c], wA, a[r]);
            b[r] = fmaf(hs[r][c], wB, b[r]);
        }
    }
#pragma unroll
    for (int r = 0; r < 8; r++) {
        A[(n0 + r) * HD + t] = a[r];
        B[(n0 + r) * HD + t] = b[r];
    }
}

// ---------------- final update (no following mm1) ----------------
__global__ __launch_bounds__(128) void k_mm2(const float* __restrict__ h,
                                             const float* __restrict__ aggr,
                                             const float* __restrict__ upd_w,
                                             const float* __restrict__ upd_b,
                                             float* __restrict__ hout) {
    __shared__ float hs[8][HD];
    __shared__ float as[8][HD];
    int t = threadIdx.x;
    int n0 = blockIdx.x * 8;
#pragma unroll
    for (int r = 0; r < 8; r++) {
        hs[r][t] = h[(n0 + r) * HD + t];
        as[r][t] = aggr[(n0 + r) * HD + t];
    }
    __syncthreads();
    float acc[8];
    float ub = upd_b[t];
#pragma unroll
    for (int r = 0; r < 8; r++) acc[r] = ub;
#pragma unroll 4
    for (int c = 0; c < HD; c++) {
        float w1 = upd_w[c * HD + t];
        float w2 = upd_w[(HD + c) * HD + t];
#pragma unroll
        for (int r = 0; r < 8; r++) {
            acc[r] = fmaf(hs[r][c], w1, acc[r]);
            acc[r] = fmaf(as[r][c], w2, acc[r]);
        }
    }
#pragma unroll
    for (int r = 0; r < 8; r++) hout[(n0 + r) * HD + t] = fmaxf(acc[r], 0.f);
}

// ---------------- decoder + per-block term partial ----------------
__global__ __launch_bounds__(256) void k_dec(const float* __restrict__ h,
                                             const float* __restrict__ dec_w,
                                             const float* __restrict__ dec_b,
                                             const float* __restrict__ term_w,
                                             float* __restrict__ out,
                                             float* __restrict__ partials) {
    __shared__ float red[4];
    int t = threadIdx.x;
    int wave = t >> 6, lane = t & 63;
    int n = blockIdx.x * 4 + wave;
    float h0 = h[n * HD + lane], h1 = h[n * HD + 64 + lane];
    float s1 = fmaf(h0, dec_w[lane], h1 * dec_w[64 + lane]);
    float s2 = fmaf(h0, term_w[lane], h1 * term_w[64 + lane]);
#pragma unroll
    for (int off = 32; off; off >>= 1) {
        s1 += __shfl_xor(s1, off);
        s2 += __shfl_xor(s2, off);
    }
    if (lane == 0) {
        out[n] = 1.f / (1.f + expf(-(s1 + dec_b[0])));
        red[wave] = s2;
    }
    __syncthreads();
    if (t == 0) partials[blockIdx.x] = red[0] + red[1] + red[2] + red[3];
}

__global__ __launch_bounds__(256) void k_term(const float* __restrict__ partials,
                                              const float* __restrict__ term_b,
                                              float* __restrict__ out) {
    __shared__ float red[256];
    int t = threadIdx.x;
    float s = 0.f;
    for (int i = t; i < 5000; i += 256) s += partials[i];
    red[t] = s;
    __syncthreads();
    for (int off = 128; off; off >>= 1) {
        if (t < off) red[t] += red[t + off];
        __syncthreads();
    }
    if (t == 0) {
        float m = red[0] / (float)NN;
        out[NN] = 1.f / (1.f + expf(-(m + term_b[0])));
    }
}

extern "C" void kernel_launch(void* const* d_in, const int* in_sizes, int n_in,
                              void* d_out, int out_size, void* d_ws, size_t ws_size,
                              hipStream_t stream) {
    const float* x        = (const float*)d_in[0];
    const int*   eidx     = (const int*)d_in[1];
    const float* eattr    = (const float*)d_in[2];
    const float* enc_w    = (const float*)d_in[3];
    const float* enc_b    = (const float*)d_in[4];
    const float* msg_w    = (const float*)d_in[5];
    const float* msg_b    = (const float*)d_in[6];
    const float* upd_w    = (const float*)d_in[7];
    const float* upd_b    = (const float*)d_in[8];
    const float* dec_w    = (const float*)d_in[9];
    const float* dec_b    = (const float*)d_in[10];
    const float* term_w   = (const float*)d_in[11];
    const float* term_b   = (const float*)d_in[12];
    float* out = (float*)d_out;

    const int* src = eidx;          // edge_index[0] = source j
    const int* dst = eidx + NE;     // edge_index[1] = target i

    char* ws = (char*)d_ws;
    size_t off = 0;
    auto alloc = [&](size_t bytes) -> void* {
        void* p = ws + off;
        off += (bytes + 255) & ~size_t(255);
        return p;
    };
    float* hA        = (float*)alloc((size_t)NN * HD * 4);
    float* hB        = (float*)alloc((size_t)NN * HD * 4);
    float* Abuf      = (float*)alloc((size_t)NN * HD * 4);
    float* Bbuf      = (float*)alloc((size_t)NN * HD * 4);
    int2*  edges     = (int2*) alloc((size_t)NE * 8);
    int*   row_ptr   = (int*)  alloc((size_t)(NN + 1) * 4);
    int*   cnt       = (int*)  alloc((size_t)NN * 4);
    int*   cursor    = (int*)  alloc((size_t)NN * 4);
    float* partials  = (float*)alloc((size_t)5000 * 4);

    // CSR build (by dst)
    k_fill_zero<<<(NN + 255) / 256, 256, 0, stream>>>(cnt, NN);
    k_hist<<<(NE + 255) / 256, 256, 0, stream>>>(dst, cnt);
    k_scan<<<1, 1024, 0, stream>>>(cnt, row_ptr, cursor);
    k_scatter<<<NPART * 128, 256, 0, stream>>>(src, dst, eattr, cursor, edges);

    // encoder + first message linear
    k_enc_mm1<<<NN / 8, 128, 0, stream>>>(x, enc_w, enc_b, msg_w, msg_b, hA, Abuf, Bbuf);

    float* hin = hA;
    float* hout = hB;
    for (int l = 0; l < NLAYERS; l++) {
        k_aggr<<<NN, 128, 0, stream>>>(Bbuf, Abuf, row_ptr, edges, msg_w);
        if (l < NLAYERS - 1) {
            k_mm2_mm1<<<NN / 8, 128, 0, stream>>>(hin, Abuf, upd_w, upd_b, msg_w, msg_b,
                                                  hout, Abuf, Bbuf);
        } else {
            k_mm2<<<NN / 8, 128, 0, stream>>>(hin, Abuf, upd_w, upd_b, hout);
        }
        float* tmp = hin; hin = hout; hout = tmp;
    }

    // decoder + termination
    k_dec<<<NN / 4, 256, 0, stream>>>(hin, dec_w, dec_b, term_w, out, partials);
    k_term<<<1, 256, 0, stream>>>(partials, term_b, out);
}